// Round 1
// 490.439 us; speedup vs baseline: 1.0061x; 1.0061x over previous
//
#include <hip/hip_runtime.h>

// GAT 3-layer on MI355X — bf16/MFMA pipeline.
//   CSR build: hist -> scan(+last-block bsum scan) -> scan3(+cursor) ->
//              bucket-partition (packed 4B pairs) -> per-bucket scatter
//   prep: weights -> bf16 transposed (+ zeroes cnt/ticket, no memset dispatch)
//   h0 = bf16(x @ lin_w + lin_b)          [MFMA 16x16x32, fp32->bf16 in-reg]
//   per layer: h' = h @ w (MFMA, attn dots fused); gather-aggregate (bf16 rows)
//   final layer: bias + L2 row normalize -> fp32 d_out.
// R6: (a) gat_agg 2-deep software pipeline — edge index prefetched two rounds
//     ahead, hs/row data one round ahead, breaking the ssrc->gather dependent
//     chain; (b) pairs packed to 4B (dstLocal:9|src:17) halving partition
//     write + scatter read; (c) 17 -> 13 dispatches (memset folded into
//     prep_w, scan2 folded into scan1 via device-scope ticket, cursor_init
//     folded into scan3).

constexpr float NEG_SLOPE = 0.2f;
#define BKT_SHIFT 9                // 512 nodes per bucket
#define BKT_N     512
#define PCHUNK    2048             // edges staged per partition block
#define SRC_BITS  17               // N=100000 < 2^17

typedef __attribute__((ext_vector_type(8))) short bf16x8;
typedef __attribute__((ext_vector_type(4))) float f32x4;

__device__ inline ushort f2bf(float x) {
    union { float f; uint u; } v; v.f = x;
    return (ushort)((v.u + 0x7FFFu + ((v.u >> 16) & 1u)) >> 16);
}
__device__ inline void bf2f(uint u, float& lo, float& hi) {
    union { uint u; float f; } a, b;
    a.u = u << 16; b.u = u & 0xFFFF0000u;
    lo = a.f; hi = b.f;
}
__device__ inline uint pk(float a, float b) {
    return (uint)f2bf(a) | ((uint)f2bf(b) << 16);
}

// ---------------- weight prep: bf16 transpose (+ cnt/ticket zero) -------------
__global__ __launch_bounds__(256) void prep_w(
    const float* __restrict__ lw, const float* __restrict__ w1,
    const float* __restrict__ w2, const float* __restrict__ w3,
    ushort* __restrict__ lwT, ushort* __restrict__ w1T,
    ushort* __restrict__ w2T, ushort* __restrict__ w3T,
    int* __restrict__ cnt, int* __restrict__ ticket, int n)
{
    const int i = blockIdx.x * 256 + threadIdx.x;
    if (i < n) cnt[i] = 0;
    if (i == 0) *ticket = 0;
    if (i < 64 * 256) {                 // lwT[n][k] = lw[k][n], K=256
        const int nn = i >> 8, k = i & 255;
        lwT[i] = f2bf(lw[k * 64 + nn]);
    } else {
        const int j = i - 64 * 256;
        if (j < 4096) {                 // wT[n][k] = w[k][n], K=64
            const int nn = j >> 6, k = j & 63;
            w1T[j] = f2bf(w1[k * 64 + nn]);
            w2T[j] = f2bf(w2[k * 64 + nn]);
            w3T[j] = f2bf(w3[k * 64 + nn]);
        }
    }
}

// ---------------- GEMM1: h0 = bf16(x[M x 256] @ lin_w + lin_b) ----------------
__global__ __launch_bounds__(256) void gemm_pre(
    const float* __restrict__ x, const ushort* __restrict__ lwT,
    const float* __restrict__ bias, ushort* __restrict__ C, int M)
{
    __shared__ __align__(16) ushort ctile[4][16][64];
    const int tid = threadIdx.x;
    const int w = tid >> 6, lane = tid & 63;
    const int rw0 = (blockIdx.x * 4 + w) * 16;
    if (rw0 >= M) return;
    const int c = lane & 15, q = lane >> 4;

    // issue all A loads back-to-back (16 global_load_dwordx4 in flight)
    const float* ap = x + (size_t)(rw0 + c) * 256 + q * 8;
    float4 pv[16];
    #pragma unroll
    for (int s = 0; s < 8; ++s) {
        pv[2 * s]     = *(const float4*)(ap + s * 32);
        pv[2 * s + 1] = *(const float4*)(ap + s * 32 + 4);
    }

    f32x4 acc[4];
    #pragma unroll
    for (int t = 0; t < 4; ++t) acc[t] = (f32x4){0.f, 0.f, 0.f, 0.f};

    #pragma unroll
    for (int s = 0; s < 8; ++s) {
        const float4 p0 = pv[2 * s];
        const float4 p1 = pv[2 * s + 1];
        bf16x8 af;
        af[0] = (short)f2bf(p0.x); af[1] = (short)f2bf(p0.y);
        af[2] = (short)f2bf(p0.z); af[3] = (short)f2bf(p0.w);
        af[4] = (short)f2bf(p1.x); af[5] = (short)f2bf(p1.y);
        af[6] = (short)f2bf(p1.z); af[7] = (short)f2bf(p1.w);
        #pragma unroll
        for (int t = 0; t < 4; ++t) {
            const bf16x8 bf = *(const bf16x8*)(lwT + (size_t)(t * 16 + c) * 256 + s * 32 + q * 8);
            acc[t] = __builtin_amdgcn_mfma_f32_16x16x32_bf16(af, bf, acc[t], 0, 0, 0);
        }
    }

    // bias + bf16 store via per-wave LDS transpose (C/D: row=q*4+reg, col=16t+c)
    #pragma unroll
    for (int t = 0; t < 4; ++t) {
        const float bv = bias[t * 16 + c];
        #pragma unroll
        for (int r = 0; r < 4; ++r)
            ctile[w][q * 4 + r][t * 16 + c] = f2bf(acc[t][r] + bv);
    }
    const int row = lane >> 2, eo = (lane & 3) * 16;
    const uint4 v0 = *(const uint4*)(&ctile[w][row][eo]);
    const uint4 v1 = *(const uint4*)(&ctile[w][row][eo + 8]);
    *(uint4*)(C + (size_t)(rw0 + row) * 64 + eo)     = v0;
    *(uint4*)(C + (size_t)(rw0 + row) * 64 + eo + 8) = v1;
}

// ---------------- layer GEMM: C = A[M x 64] @ w, + attn dots ------------------
__global__ __launch_bounds__(256) void gemm_layer(
    const ushort* __restrict__ A, const ushort* __restrict__ WT,
    const float* __restrict__ a_s, const float* __restrict__ a_d,
    ushort* __restrict__ C, float* __restrict__ hs, float* __restrict__ hd, int M)
{
    __shared__ __align__(16) ushort ctile[4][16][64];
    const int tid = threadIdx.x;
    const int w = tid >> 6, lane = tid & 63;
    const int rw0 = (blockIdx.x * 4 + w) * 16;
    if (rw0 >= M) return;
    const int c = lane & 15, q = lane >> 4;

    const ushort* ap = A + (size_t)(rw0 + c) * 64 + q * 8;
    const bf16x8 a0 = *(const bf16x8*)(ap);
    const bf16x8 a1 = *(const bf16x8*)(ap + 32);

    f32x4 acc[4];
    #pragma unroll
    for (int t = 0; t < 4; ++t) {
        const ushort* bp = WT + (size_t)(t * 16 + c) * 64 + q * 8;
        const bf16x8 b0 = *(const bf16x8*)(bp);
        const bf16x8 b1 = *(const bf16x8*)(bp + 32);
        f32x4 a = (f32x4){0.f, 0.f, 0.f, 0.f};
        a = __builtin_amdgcn_mfma_f32_16x16x32_bf16(a0, b0, a, 0, 0, 0);
        a = __builtin_amdgcn_mfma_f32_16x16x32_bf16(a1, b1, a, 0, 0, 0);
        acc[t] = a;
    }

    // attn dots: hs[r] = sum_n C[r][n]*a_s[n]; lane holds cols {16t+c}
    float ps[4] = {0.f, 0.f, 0.f, 0.f}, pd[4] = {0.f, 0.f, 0.f, 0.f};
    #pragma unroll
    for (int t = 0; t < 4; ++t) {
        const float as = a_s[t * 16 + c], ad = a_d[t * 16 + c];
        #pragma unroll
        for (int r = 0; r < 4; ++r) {
            ps[r] = fmaf(acc[t][r], as, ps[r]);
            pd[r] = fmaf(acc[t][r], ad, pd[r]);
        }
    }
    #pragma unroll
    for (int r = 0; r < 4; ++r) {
        #pragma unroll
        for (int off = 1; off < 16; off <<= 1) {
            ps[r] += __shfl_xor(ps[r], off);
            pd[r] += __shfl_xor(pd[r], off);
        }
    }
    if (c == 0) {
        #pragma unroll
        for (int r = 0; r < 4; ++r) {
            hs[rw0 + q * 4 + r] = ps[r];
            hd[rw0 + q * 4 + r] = pd[r];
        }
    }

    // bf16 store via per-wave LDS transpose
    #pragma unroll
    for (int t = 0; t < 4; ++t)
        #pragma unroll
        for (int r = 0; r < 4; ++r)
            ctile[w][q * 4 + r][t * 16 + c] = f2bf(acc[t][r]);
    const int row = lane >> 2, eo = (lane & 3) * 16;
    const uint4 v0 = *(const uint4*)(&ctile[w][row][eo]);
    const uint4 v1 = *(const uint4*)(&ctile[w][row][eo + 8]);
    *(uint4*)(C + (size_t)(rw0 + row) * 64 + eo)     = v0;
    *(uint4*)(C + (size_t)(rw0 + row) * 64 + eo + 8) = v1;
}

// ---------------- CSR build --------------------------------------------------
__global__ __launch_bounds__(256) void edge_hist(
    const int* __restrict__ dst, int* __restrict__ cnt, int e)
{
    const int i0 = (blockIdx.x * 256 + threadIdx.x) * 4;
    if (i0 + 3 < e) {
        const int4 d = *(const int4*)(dst + i0);
        atomicAdd(&cnt[d.x], 1); atomicAdd(&cnt[d.y], 1);
        atomicAdd(&cnt[d.z], 1); atomicAdd(&cnt[d.w], 1);
    } else {
        for (int k = i0; k < e; ++k) atomicAdd(&cnt[dst[k]], 1);
    }
}

// scan1: per-1024-block exclusive scan; last block (device-scope ticket)
// additionally scans bsum[] so a separate scan2 dispatch is unnecessary.
__global__ __launch_bounds__(256) void scan1(
    const int* __restrict__ cnt, int* __restrict__ out,
    int* __restrict__ bsum, int* __restrict__ ticket, int n, int nblk)
{
    __shared__ int wsum[4];
    __shared__ int amLastS;
    const int tid  = threadIdx.x;
    const int lane = tid & 63;
    const int w    = tid >> 6;
    const int base = blockIdx.x * 1024;
    int vals[4];
    int tsum = 0;
    #pragma unroll
    for (int i = 0; i < 4; ++i) {
        const int idx = base + tid * 4 + i;
        vals[i] = (idx < n) ? cnt[idx] : 0;
        tsum += vals[i];
    }
    int x = tsum;
    #pragma unroll
    for (int off = 1; off < 64; off <<= 1) {
        const int y = __shfl_up(x, off);
        if (lane >= off) x += y;
    }
    if (lane == 63) wsum[w] = x;
    __syncthreads();
    int wofs = 0;
    for (int k = 0; k < w; ++k) wofs += wsum[k];
    int excl = wofs + x - tsum;
    #pragma unroll
    for (int i = 0; i < 4; ++i) {
        const int idx = base + tid * 4 + i;
        if (idx < n) out[idx] = excl;
        excl += vals[i];
    }
    if (tid == 255) {
        bsum[blockIdx.x] = wofs + x;
        __threadfence();                       // release bsum write
        amLastS = (atomicAdd(ticket, 1) == nblk - 1) ? 1 : 0;
    }
    __syncthreads();
    if (amLastS) {                             // last block scans bsum[nblk]
        __threadfence();                       // acquire others' bsum writes
        const int v2 = (tid < nblk) ? bsum[tid] : 0;
        int x2 = v2;
        #pragma unroll
        for (int off = 1; off < 64; off <<= 1) {
            const int y = __shfl_up(x2, off);
            if (lane >= off) x2 += y;
        }
        if (lane == 63) wsum[w] = x2;
        __syncthreads();
        int c2 = 0;
        for (int k = 0; k < w; ++k) c2 += wsum[k];
        if (tid < nblk) bsum[tid] = c2 + x2 - v2;
    }
}

// scan3: add scanned block sums; also emits per-bucket cursors and offs[n].
__global__ __launch_bounds__(256) void scan3(
    int* __restrict__ out, const int* __restrict__ bsum,
    int* __restrict__ gcur, int n, int total)
{
    const int idx = blockIdx.x * blockDim.x + threadIdx.x;
    if (idx < n) {
        const int v = out[idx] + bsum[idx >> 10];
        out[idx] = v;
        if ((idx & (BKT_N - 1)) == 0) gcur[idx >> BKT_SHIFT] = v;
    }
    if (idx == 0) out[n] = total;
}

// Phase 1: bucket edges by dst>>9 into CSR-aligned regions, coalesced runs.
// pairs packed to 4B: (dst & 511) << 17 | src   (src < 2^17).
__global__ __launch_bounds__(256) void edge_partition(
    const int* __restrict__ src, const int* __restrict__ dst,
    int* __restrict__ gcursor, int* __restrict__ pairs, int e, int nb)
{
    __shared__ int stage[PCHUNK];
    __shared__ unsigned char sbkt[PCHUNK];
    __shared__ int lcnt[256];
    __shared__ int lstart[256];
    __shared__ int lfill[256];
    __shared__ int gbase[256];
    __shared__ int wsum[4];

    const int tid  = threadIdx.x;
    const int lane = tid & 63;
    const int w    = tid >> 6;
    const int base = blockIdx.x * PCHUNK;
    const int cnt_here = min(PCHUNK, e - base);

    lcnt[tid] = 0; lfill[tid] = 0;
    __syncthreads();

    // pass 1: bucket histogram (dst only)
    for (int i = tid; i < cnt_here; i += 256)
        atomicAdd(&lcnt[dst[base + i] >> BKT_SHIFT], 1);
    __syncthreads();

    // exclusive scan of lcnt[256] -> lstart; reserve global runs
    const int v = lcnt[tid];
    int x = v;
    #pragma unroll
    for (int off = 1; off < 64; off <<= 1) {
        const int y = __shfl_up(x, off);
        if (lane >= off) x += y;
    }
    if (lane == 63) wsum[w] = x;
    __syncthreads();
    int carry = 0;
    for (int k = 0; k < w; ++k) carry += wsum[k];
    lstart[tid] = carry + x - v;
    if (tid < nb && v > 0) gbase[tid] = atomicAdd(&gcursor[tid], v);
    __syncthreads();

    // pass 2: re-read (dst L2-hot) and stage bucket-major, packed
    for (int i = tid; i < cnt_here; i += 256) {
        const int d = dst[base + i];
        const int s = src[base + i];
        const int b = d >> BKT_SHIFT;
        const int p = lstart[b] + atomicAdd(&lfill[b], 1);
        stage[p] = ((d & (BKT_N - 1)) << SRC_BITS) | s;
        sbkt[p]  = (unsigned char)b;
    }
    __syncthreads();

    // contiguous write-out per bucket run
    for (int t = tid; t < cnt_here; t += 256) {
        const int b = sbkt[t];
        pairs[gbase[b] + (t - lstart[b])] = stage[t];
    }
}

// Phase 2: one block per bucket; per-node cursors in LDS; writes confined
// to this block's contiguous ssrc region (single-XCD line merging).
__global__ __launch_bounds__(256) void bucket_scatter(
    const int* __restrict__ pairs, const int* __restrict__ offs,
    int* __restrict__ ssrc, int n)
{
    __shared__ int pos[BKT_N];
    const int node0 = blockIdx.x << BKT_SHIFT;
    const int node1 = min(n, node0 + BKT_N);
    const int tid = threadIdx.x;
    for (int i = tid; i < node1 - node0; i += 256) pos[i] = offs[node0 + i];
    __syncthreads();
    const int e0 = offs[node0];
    const int e1 = offs[node1];
    for (int j = e0 + tid; j < e1; j += 256) {
        const int pr = pairs[j];
        const int p = atomicAdd(&pos[pr >> SRC_BITS], 1);
        ssrc[p] = pr & ((1 << SRC_BITS) - 1);
    }
}

// ---------------- gather aggregation (bf16 rows) -----------------------------
// One wave per node; 8 edge slots x 8 lanes (16 B = 8 bf16 per lane).
// 2-deep software pipeline: edge index prefetched two rounds ahead, hs/row
// data one round ahead — the ssrc->gather dependent chain never stalls a
// round. Invalid prefetch lanes clamp to the current index (MSHR-coalesced).
// MODE 0: +bias, ReLU -> bf16 out.  MODE 1: +bias, L2 normalize -> fp32 out.
template <int MODE>
__global__ __launch_bounds__(256) void gat_agg(
    const ushort* __restrict__ hp, const float* __restrict__ hs,
    const float* __restrict__ hd, const int* __restrict__ offs,
    const int* __restrict__ ssrc, const float* __restrict__ bias,
    void* __restrict__ outv, int n)
{
    const int wid  = (blockIdx.x * blockDim.x + threadIdx.x) >> 6;
    const int lane = threadIdx.x & 63;
    if (wid >= n) return;
    const int sub = lane >> 3;          // edge slot 0..7
    const int f0  = (lane & 7) * 8;     // feature offset (8 bf16)

    const int start = offs[wid];
    const int end   = offs[wid + 1];
    const float hdi = hd[wid];

    // index prefetch (two rounds deep)
    int j = start + sub;
    bool vC = j < end;
    bool vN = j + 8 < end;
    int sC = vC ? ssrc[j]     : wid;
    int sN = vN ? ssrc[j + 8] : sC;

    float den = 0.f;
    float acc[8] = {};

    if (sub == 0) {   // self-loop
        const uint4 t = *(const uint4*)(hp + (size_t)wid * 64 + f0);
        float e = hs[wid] + hdi;
        e = (e > 0.f) ? e : NEG_SLOPE * e;
        const float ex = __expf(e);
        float f[8];
        bf2f(t.x, f[0], f[1]); bf2f(t.y, f[2], f[3]);
        bf2f(t.z, f[4], f[5]); bf2f(t.w, f[6], f[7]);
        den = ex;
        #pragma unroll
        for (int i = 0; i < 8; ++i) acc[i] = ex * f[i];
    }

    // data prefetch for round 0
    float hsC = hs[sC];
    uint4 tC  = *(const uint4*)(hp + (size_t)sC * 64 + f0);

    while (vC) {
        const bool vNN = j + 16 < end;
        const int  sNN = vNN ? ssrc[j + 16] : sN;   // index 2 ahead
        const float hsN = hs[sN];                    // data 1 ahead
        const uint4 tN  = *(const uint4*)(hp + (size_t)sN * 64 + f0);

        float e2 = hsC + hdi;
        e2 = (e2 > 0.f) ? e2 : NEG_SLOPE * e2;
        const float ex2 = __expf(e2);
        float f[8];
        bf2f(tC.x, f[0], f[1]); bf2f(tC.y, f[2], f[3]);
        bf2f(tC.z, f[4], f[5]); bf2f(tC.w, f[6], f[7]);
        den += ex2;
        #pragma unroll
        for (int i = 0; i < 8; ++i) acc[i] = fmaf(ex2, f[i], acc[i]);

        vC = vN; vN = vNN; sC = sN; sN = sNN; hsC = hsN; tC = tN;
        j += 8;
    }

    // reduce the 8 edge slots (lanes with same f0)
    #pragma unroll
    for (int off = 8; off < 64; off <<= 1) {
        den += __shfl_xor(den, off);
        #pragma unroll
        for (int i = 0; i < 8; ++i) acc[i] += __shfl_xor(acc[i], off);
    }

    const float4 bv0 = *(const float4*)(bias + f0);
    const float4 bv1 = *(const float4*)(bias + f0 + 4);
    const float bb[8] = {bv0.x, bv0.y, bv0.z, bv0.w, bv1.x, bv1.y, bv1.z, bv1.w};
    const float inv = 1.f / (den + 1e-16f);
    float v[8];
    #pragma unroll
    for (int i = 0; i < 8; ++i) v[i] = acc[i] * inv + bb[i];

    if (MODE == 0) {
        #pragma unroll
        for (int i = 0; i < 8; ++i) v[i] = fmaxf(v[i], 0.f);
        if (sub == 0) {
            uint4 o;
            o.x = pk(v[0], v[1]); o.y = pk(v[2], v[3]);
            o.z = pk(v[4], v[5]); o.w = pk(v[6], v[7]);
            *(uint4*)((ushort*)outv + (size_t)wid * 64 + f0) = o;
        }
    } else {
        float sq = 0.f;
        #pragma unroll
        for (int i = 0; i < 8; ++i) sq += v[i] * v[i];
        #pragma unroll
        for (int off = 1; off < 8; off <<= 1) sq += __shfl_xor(sq, off);
        const float s = 1.f / fmaxf(sqrtf(sq), 1e-12f);
        if (sub == 0) {
            float* op = (float*)outv + (size_t)wid * 64 + f0;
            float4 o0, o1;
            o0.x = v[0] * s; o0.y = v[1] * s; o0.z = v[2] * s; o0.w = v[3] * s;
            o1.x = v[4] * s; o1.y = v[5] * s; o1.z = v[6] * s; o1.w = v[7] * s;
            *(float4*)(op)     = o0;
            *(float4*)(op + 4) = o1;
        }
    }
}

// ---------------- launch -----------------------------------------------------
extern "C" void kernel_launch(void* const* d_in, const int* in_sizes, int n_in,
                              void* d_out, int out_size, void* d_ws, size_t ws_size,
                              hipStream_t stream)
{
    const float* x     = (const float*)d_in[0];
    const int*   src   = (const int*)d_in[1];
    const int*   dst   = (const int*)d_in[2];
    const float* lin_w = (const float*)d_in[3];
    const float* lin_b = (const float*)d_in[4];
    const float* w1  = (const float*)d_in[5];
    const float* a1s = (const float*)d_in[6];
    const float* a1d = (const float*)d_in[7];
    const float* b1  = (const float*)d_in[8];
    const float* w2  = (const float*)d_in[9];
    const float* a2s = (const float*)d_in[10];
    const float* a2d = (const float*)d_in[11];
    const float* b2  = (const float*)d_in[12];
    const float* w3  = (const float*)d_in[13];
    const float* a3s = (const float*)d_in[14];
    const float* a3d = (const float*)d_in[15];
    const float* b3  = (const float*)d_in[16];

    const int n = in_sizes[0] / 256;   // 100000 nodes
    const int E = in_sizes[1];         // 1280000 edges
    const int nb = (n + BKT_N - 1) >> BKT_SHIFT;

    char* wsp = (char*)d_ws;
    auto alloc = [&](size_t bytes) -> void* {
        void* p = (void*)wsp;
        wsp += (bytes + 255) & ~(size_t)255;
        return p;
    };
    ushort* bufA = (ushort*)alloc((size_t)n * 64 * sizeof(ushort));   // bf16 h
    ushort* bufB = (ushort*)alloc((size_t)n * 64 * sizeof(ushort));   // bf16 h'
    float*  hs   = (float*)alloc((size_t)n * sizeof(float));
    float*  hd   = (float*)alloc((size_t)n * sizeof(float));
    int*    offs = (int*)alloc((size_t)(n + 1) * sizeof(int));
    int*    cnt  = (int*)alloc((size_t)n * sizeof(int));
    int*    bsum = (int*)alloc(1024 * sizeof(int));
    int*    gcur = (int*)alloc(256 * sizeof(int));
    int*    tick = (int*)alloc(256 * sizeof(int));
    int*    ssrc = (int*)alloc((size_t)E * sizeof(int));
    int*    pairs = (int*)alloc((size_t)E * sizeof(int));
    ushort* lwT = (ushort*)alloc(64 * 256 * sizeof(ushort));
    ushort* w1T = (ushort*)alloc(64 * 64 * sizeof(ushort));
    ushort* w2T = (ushort*)alloc(64 * 64 * sizeof(ushort));
    ushort* w3T = (ushort*)alloc(64 * 64 * sizeof(ushort));

    const int nodeWaveBlocks = (n + 3) / 4;
    const int gemmBlocks = (n + 63) / 64;
    const int nScanBlocks = (n + 1023) / 1024;
    const int partBlocks = (E + PCHUNK - 1) / PCHUNK;
    const int histBlocks = (E / 4 + 255) / 256 + 1;

    // ---- weight prep (zeroes cnt/ticket) + CSR build ----
    prep_w<<<(n + 255) / 256, 256, 0, stream>>>(
        lin_w, w1, w2, w3, lwT, w1T, w2T, w3T, cnt, tick, n);
    edge_hist<<<histBlocks, 256, 0, stream>>>(dst, cnt, E);
    scan1<<<nScanBlocks, 256, 0, stream>>>(cnt, offs, bsum, tick, n, nScanBlocks);
    scan3<<<(n + 255) / 256, 256, 0, stream>>>(offs, bsum, gcur, n, E);
    edge_partition<<<partBlocks, 256, 0, stream>>>(src, dst, gcur, pairs, E, nb);
    bucket_scatter<<<nb, 256, 0, stream>>>(pairs, offs, ssrc, n);

    // ---- h0 = bf16(x @ lin_w + lin_b) ----
    gemm_pre<<<gemmBlocks, 256, 0, stream>>>(x, lwT, lin_b, bufA, n);

    // ---- layer 1 ----
    gemm_layer<<<gemmBlocks, 256, 0, stream>>>(bufA, w1T, a1s, a1d, bufB, hs, hd, n);
    gat_agg<0><<<nodeWaveBlocks, 256, 0, stream>>>(bufB, hs, hd, offs, ssrc, b1, bufA, n);

    // ---- layer 2 ----
    gemm_layer<<<gemmBlocks, 256, 0, stream>>>(bufA, w2T, a2s, a2d, bufB, hs, hd, n);
    gat_agg<0><<<nodeWaveBlocks, 256, 0, stream>>>(bufB, hs, hd, offs, ssrc, b2, bufA, n);

    // ---- layer 3 + normalize -> d_out ----
    gemm_layer<<<gemmBlocks, 256, 0, stream>>>(bufA, w3T, a3s, a3d, bufB, hs, hd, n);
    gat_agg<1><<<nodeWaveBlocks, 256, 0, stream>>>(bufB, hs, hd, offs, ssrc, b3,
                                                   d_out, n);
}